// Round 2
// baseline (41859.393 us; speedup 1.0000x reference)
//
#include <hip/hip_runtime.h>
#include <hip/hip_cooperative_groups.h>
#include <math.h>

namespace cg = cooperative_groups;

// Problem constants
#define TY 128
#define B  64
#define TX 400
#define IN 512
#define H  512
#define C  512
#define NH 8
#define DH 64
#define G4 2048   // 4*H

#define MAXBLK 768

__device__ __forceinline__ float sigf(float x) { return 1.f / (1.f + __expf(-x)); }

// ---------------------------------------------------------------------------
// Generic tiled GEMM (precompute only): Out[r,n] = sum_k A[r,k]*W[n,k] + b1 (+b2)
// ---------------------------------------------------------------------------
__global__ __launch_bounds__(256) void gemm_bias(
    const float* __restrict__ A, const float* __restrict__ W,
    const float* __restrict__ bias1, const float* __restrict__ bias2,
    float* __restrict__ Out, int N, int K) {
  __shared__ float As[16][68];
  __shared__ float Ws[16][68];
  int tid = threadIdx.x;
  int n0 = blockIdx.x * 64;
  int r0 = blockIdx.y * 64;
  int tx = tid & 15, ty = tid >> 4;
  float acc[4][4] = {};
  for (int k0 = 0; k0 < K; k0 += 16) {
    #pragma unroll
    for (int i = 0; i < 4; i++) {
      int idx = tid + i * 256;
      int r = idx >> 4, k = idx & 15;
      As[k][r] = A[(size_t)(r0 + r) * K + k0 + k];
      Ws[k][r] = W[(size_t)(n0 + r) * K + k0 + k];
    }
    __syncthreads();
    #pragma unroll
    for (int k = 0; k < 16; k++) {
      float a[4], w[4];
      #pragma unroll
      for (int i = 0; i < 4; i++) a[i] = As[k][ty * 4 + i];
      #pragma unroll
      for (int j = 0; j < 4; j++) w[j] = Ws[k][tx * 4 + j];
      #pragma unroll
      for (int i = 0; i < 4; i++)
        #pragma unroll
        for (int j = 0; j < 4; j++) acc[i][j] += a[i] * w[j];
    }
    __syncthreads();
  }
  #pragma unroll
  for (int i = 0; i < 4; i++) {
    int r = r0 + ty * 4 + i;
    #pragma unroll
    for (int j = 0; j < 4; j++) {
      int n = n0 + tx * 4 + j;
      float v = acc[i][j];
      if (bias1) v += bias1[n];
      if (bias2) v += bias2[n];
      Out[(size_t)r * N + n] = v;
    }
  }
}

// ---------------------------------------------------------------------------
// Persistent cooperative step kernel
// ---------------------------------------------------------------------------
struct SMem {
  union {
    struct { float As[16][68]; float Ws[16][68]; } g;                     // 8704 B
    struct { float wsh[512]; float sm[4]; float ssum[4]; float buf[4][64]; } sa;
    struct { float s_att[512]; float s_o[512]; float rs[4]; float rq[4]; } cl;
  } u;
};

// 64-row tile GEMM: rows = 64 batch rows, cols [n0,n0+64), K slice [kbeg,kbeg+KS).
template<bool SPLITA, bool ATOMIC>
__device__ __forceinline__ void gemm_tile64(
    const float* __restrict__ A1, const float* __restrict__ A2,
    const float* __restrict__ W, float* __restrict__ Out,
    const int N, const int Ktot, const int kbeg, const int KS,
    const int n0, const int sliceIdx, SMem* sh) {
  const int tid = threadIdx.x;
  const int tx = tid & 15, ty = tid >> 4;
  float acc[4][4] = {};
  for (int k0 = kbeg; k0 < kbeg + KS; k0 += 16) {
    #pragma unroll
    for (int i = 0; i < 4; i++) {
      int idx = tid + i * 256;
      int r = idx >> 4, k = idx & 15;
      int kk = k0 + k;
      float av;
      if constexpr (SPLITA) {
        av = (kk < 512) ? A1[r * 512 + kk] : A2[r * 512 + (kk - 512)];
      } else {
        av = A1[r * 512 + kk];
      }
      sh->u.g.As[k][r] = av;
      sh->u.g.Ws[k][r] = W[(size_t)(n0 + r) * Ktot + kk];
    }
    __syncthreads();
    #pragma unroll
    for (int k = 0; k < 16; k++) {
      float a[4], w[4];
      #pragma unroll
      for (int i = 0; i < 4; i++) a[i] = sh->u.g.As[k][ty * 4 + i];
      #pragma unroll
      for (int j = 0; j < 4; j++) w[j] = sh->u.g.Ws[k][tx * 4 + j];
      #pragma unroll
      for (int i = 0; i < 4; i++)
        #pragma unroll
        for (int j = 0; j < 4; j++) acc[i][j] += a[i] * w[j];
    }
    __syncthreads();
  }
  if constexpr (ATOMIC) {
    #pragma unroll
    for (int i = 0; i < 4; i++)
      #pragma unroll
      for (int j = 0; j < 4; j++)
        atomicAdd(&Out[(size_t)(ty * 4 + i) * N + n0 + tx * 4 + j], acc[i][j]);
  } else {
    float* Pp = Out + (size_t)sliceIdx * 64 * N;
    #pragma unroll
    for (int i = 0; i < 4; i++)
      #pragma unroll
      for (int j = 0; j < 4; j++)
        Pp[(size_t)(ty * 4 + i) * N + n0 + tx * 4 + j] = acc[i][j];
  }
}

// e[b][h][t] = xm * sum_d tanh(pctx + hq + acc*Wcov) * U  — one wave per (t,b)
__device__ __forceinline__ void e_phase(
    const float* __restrict__ pctx, const float* __restrict__ hq,
    const float* __restrict__ acc, const float* __restrict__ Wcov,
    const float* __restrict__ U, const float* __restrict__ xmask,
    float* __restrict__ e) {
  const int wv = threadIdx.x >> 6, lane = threadIdx.x & 63;
  const int stride = gridDim.x * 4;
  for (int pair = blockIdx.x * 4 + wv; pair < TX * B; pair += stride) {
    const int t = pair >> 6, b = pair & 63;
    const float* prow = pctx + (size_t)pair * 512;
    const float a = acc[b * TX + t];
    const float xm = xmask[pair];
    float v[8];
    #pragma unroll
    for (int h = 0; h < 8; h++) {
      int c = h * 64 + lane;
      float uu = tanhf(prow[c] + hq[b * 512 + c] + a * Wcov[c]);
      v[h] = uu * U[c];
    }
    #pragma unroll
    for (int off = 32; off; off >>= 1)
      #pragma unroll
      for (int h = 0; h < 8; h++) v[h] += __shfl_xor(v[h], off);
    if (lane == 0) {
      float* ep = e + (size_t)(b * 8) * TX + t;
      #pragma unroll
      for (int h = 0; h < 8; h++) ep[h * TX] = v[h] * xm;
    }
  }
}

// fused softmax (over t) + attention-weighted pv sum, one unit per (b,h)
__device__ __forceinline__ void smax_att_block(
    int bh, const float* __restrict__ e, const float* __restrict__ xmask,
    float* __restrict__ acc, float* __restrict__ dist, float* __restrict__ Cs,
    const float* __restrict__ pv, float* __restrict__ att, SMem* sh) {
  const int b = bh >> 3, h = bh & 7;
  const float* erow = e + (size_t)bh * TX;
  const int tid = threadIdx.x, wv = tid >> 6, lane = tid & 63;
  float e0 = (tid < TX) ? erow[tid] : -1e30f;
  float e1 = (tid + 256 < TX) ? erow[tid + 256] : -1e30f;
  float m = fmaxf(e0, e1);
  #pragma unroll
  for (int off = 32; off; off >>= 1) m = fmaxf(m, __shfl_xor(m, off));
  if (lane == 0) sh->u.sa.sm[wv] = m;
  __syncthreads();
  m = fmaxf(fmaxf(sh->u.sa.sm[0], sh->u.sa.sm[1]),
            fmaxf(sh->u.sa.sm[2], sh->u.sa.sm[3]));
  float xm0 = (tid < TX) ? xmask[tid * 64 + b] : 0.f;
  float xm1 = (tid + 256 < TX) ? xmask[(tid + 256) * 64 + b] : 0.f;
  float w0 = (tid < TX) ? __expf(e0 - m) * xm0 : 0.f;
  float w1 = (tid + 256 < TX) ? __expf(e1 - m) * xm1 : 0.f;
  float s = w0 + w1;
  #pragma unroll
  for (int off = 32; off; off >>= 1) s += __shfl_xor(s, off);
  if (lane == 0) sh->u.sa.ssum[wv] = s;
  __syncthreads();
  s = sh->u.sa.ssum[0] + sh->u.sa.ssum[1] + sh->u.sa.ssum[2] + sh->u.sa.ssum[3] + 1e-6f;
  float inv = 1.f / s;
  w0 *= inv; w1 *= inv;
  sh->u.sa.wsh[tid] = w0;
  sh->u.sa.wsh[tid + 256] = w1;
  if (h == 0) {
    if (tid < TX) {
      float a = acc[b * TX + tid];
      dist[b * TX + tid] = w0;
      Cs[b * TX + tid] = a;
      acc[b * TX + tid] = a + w0;
    }
    if (tid + 256 < TX) {
      float a = acc[b * TX + tid + 256];
      dist[b * TX + tid + 256] = w1;
      Cs[b * TX + tid + 256] = a;
      acc[b * TX + tid + 256] = a + w1;
    }
  }
  __syncthreads();
  float pacc = 0.f;
  for (int tt = wv; tt < TX; tt += 4)
    pacc += sh->u.sa.wsh[tt] * pv[((size_t)(tt * 64 + b) * 8 + h) * 64 + lane];
  sh->u.sa.buf[wv][lane] = pacc;
  __syncthreads();
  if (wv == 0)
    att[b * 512 + h * 64 + lane] = sh->u.sa.buf[0][lane] + sh->u.sa.buf[1][lane] +
                                   sh->u.sa.buf[2][lane] + sh->u.sa.buf[3][lane];
  __syncthreads();   // LDS reuse guard (unit loop)
}

// att @ W_concat^T + LayerNorm, one unit per b
__device__ __forceinline__ void concat_block(
    int b, const float* __restrict__ att, const float* __restrict__ Wcat,
    const float* __restrict__ ln_g, const float* __restrict__ ln_b,
    float* __restrict__ atts_out, SMem* sh) {
  const int tid = threadIdx.x, wv = tid >> 6, lane = tid & 63;
  sh->u.cl.s_att[tid] = att[b * 512 + tid];
  sh->u.cl.s_att[tid + 256] = att[b * 512 + tid + 256];
  __syncthreads();
  for (int j = wv; j < 512; j += 4) {
    const float* wr = Wcat + (size_t)j * 512;
    float pq = 0.f;
    #pragma unroll
    for (int q = 0; q < 8; q++) pq += sh->u.cl.s_att[q * 64 + lane] * wr[q * 64 + lane];
    #pragma unroll
    for (int off = 32; off; off >>= 1) pq += __shfl_xor(pq, off);
    if (lane == 0) sh->u.cl.s_o[j] = pq;
  }
  __syncthreads();
  float x0 = sh->u.cl.s_o[tid], x1 = sh->u.cl.s_o[tid + 256];
  float sum = x0 + x1, sq = x0 * x0 + x1 * x1;
  #pragma unroll
  for (int off = 32; off; off >>= 1) {
    sum += __shfl_xor(sum, off);
    sq += __shfl_xor(sq, off);
  }
  if (lane == 0) { sh->u.cl.rs[wv] = sum; sh->u.cl.rq[wv] = sq; }
  __syncthreads();
  sum = sh->u.cl.rs[0] + sh->u.cl.rs[1] + sh->u.cl.rs[2] + sh->u.cl.rs[3];
  sq  = sh->u.cl.rq[0] + sh->u.cl.rq[1] + sh->u.cl.rq[2] + sh->u.cl.rq[3];
  float mu = sum * (1.f / 512.f);
  float var = sq * (1.f / 512.f) - mu * mu;
  float rstd = rsqrtf(var + 1e-5f);
  atts_out[b * 512 + tid] = (x0 - mu) * rstd * ln_g[tid] + ln_b[tid];
  atts_out[b * 512 + tid + 256] =
      (x1 - mu) * rstd * ln_g[tid + 256] + ln_b[tid + 256];
  __syncthreads();   // LDS reuse guard (unit loop)
}

struct Params {
  const float *h0, *c0, *x_mask, *y_mask, *init_cov;
  const float *W_hh, *W_comb, *U_att, *W_cov, *W_cat, *ln_g, *ln_b;
  const float *xW, *pctx, *pv;
  float *gatesP, *hq, *ebuf, *attbuf, *accbuf;
  float *hs, *cs, *ss, *atts, *dists, *Cs;
};

__global__ __launch_bounds__(256, 2) void k_steps(Params p) {
  cg::grid_group grid = cg::this_grid();
  __shared__ SMem sh;
  const int tid = threadIdx.x;
  const int NB = gridDim.x;

  // ---- prologue: coverage init + gatesP(0) from h0 (grid-stride, any NB)
  for (int i = blockIdx.x * 256 + tid; i < B * TX; i += NB * 256)
    p.accbuf[i] = p.init_cov[i];
  for (int g = blockIdx.x; g < 256; g += NB) {   // 32 n-tiles x 8 k-slices
    gemm_tile64<false, false>(p.h0, nullptr, p.W_hh, p.gatesP,
                              G4, 512, (g >> 5) * 64, 64, (g & 31) * 64, g >> 5, &sh);
  }
  grid.sync();

  for (int t = 0; t < TY; t++) {
    const float* hp = t ? p.hs + (size_t)(t - 1) * B * H : p.h0;
    const float* cp = t ? p.cs + (size_t)(t - 1) * B * H : p.c0;
    float* hs_t = p.hs + (size_t)t * B * H;
    float* cs_t = p.cs + (size_t)t * B * H;
    float* ss_t = p.ss + (size_t)t * B * H;

    // ---- C-phase: LSTM cell(t) [units 0..127] ; zero hq [units 128..255]
    for (int u = blockIdx.x; u < 256; u += NB) {
      int idx = u * 256 + tid;
      if (idx < B * H) {
        const float* xWt = p.xW + (size_t)t * B * G4;
        int b = idx >> 9, mm = idx & 511;
        float g4[4];
        #pragma unroll
        for (int q = 0; q < 4; q++) {
          int j = q * 512 + mm;
          float g = xWt[b * 2048 + j];
          #pragma unroll
          for (int s = 0; s < 8; s++) g += p.gatesP[(size_t)(s * 64 + b) * 2048 + j];
          g4[q] = g;
        }
        float i_ = sigf(g4[0]);
        float f_ = sigf(g4[1]);
        float gg = tanhf(g4[2]);
        float o_ = sigf(g4[3]);
        float cpv = cp[idx], hpv = hp[idx];
        float c1 = f_ * cpv + i_ * gg;
        float h1 = o_ * tanhf(c1);
        float ym = p.y_mask[t * B + b];
        h1 = ym * h1 + (1.f - ym) * hpv;
        c1 = ym * c1 + (1.f - ym) * cpv;
        hs_t[idx] = h1;
        ss_t[idx] = h1;
        cs_t[idx] = c1;
      } else {
        p.hq[idx - B * H] = 0.f;
      }
    }
    grid.sync();

    // ---- D-phase: hq += [h1,c1]@W_comb^T (atomic split-K) [units 0..63]
    //               concat+LN of step t-1 [units 64..127]
    for (int u = blockIdx.x; u < 128; u += NB) {
      if (u < 64) {
        gemm_tile64<true, true>(hs_t, cs_t, p.W_comb, p.hq,
                                C, 1024, (u >> 3) * 128, 128, (u & 7) * 64, 0, &sh);
      } else if (t > 0) {
        concat_block(u - 64, p.attbuf, p.W_cat, p.ln_g, p.ln_b,
                     p.atts + (size_t)(t - 1) * B * C, &sh);
      }
    }
    grid.sync();

    // ---- A-phase: e scores(t)
    e_phase(p.pctx, p.hq, p.accbuf, p.W_cov, p.U_att, p.x_mask, p.ebuf);
    grid.sync();

    // ---- B-phase: softmax+att(t) [units 0..511] ; gatesP(t+1) [units 512..767]
    {
      int umax = (t + 1 < TY) ? 768 : 512;
      for (int u = blockIdx.x; u < umax; u += NB) {
        if (u < 512) {
          smax_att_block(u, p.ebuf, p.x_mask, p.accbuf,
                         p.dists + (size_t)t * B * TX, p.Cs + (size_t)t * B * TX,
                         p.pv, p.attbuf, &sh);
        } else {
          int g = u - 512;
          gemm_tile64<false, false>(hs_t, nullptr, p.W_hh, p.gatesP,
                                    G4, 512, (g >> 5) * 64, 64, (g & 31) * 64, g >> 5, &sh);
        }
      }
    }
    grid.sync();
  }

  // ---- epilogue: concat+LN of final step
  for (int u = blockIdx.x; u < 64; u += NB)
    concat_block(u, p.attbuf, p.W_cat, p.ln_g, p.ln_b,
                 p.atts + (size_t)(TY - 1) * B * C, &sh);
}

// ---------------------------------------------------------------------------
extern "C" void kernel_launch(void* const* d_in, const int* in_sizes, int n_in,
                              void* d_out, int out_size, void* d_ws, size_t ws_size,
                              hipStream_t stream) {
  const float* y_emb    = (const float*)d_in[0];
  const float* context  = (const float*)d_in[1];
  const float* h0       = (const float*)d_in[2];
  const float* c0       = (const float*)d_in[3];
  const float* x_mask   = (const float*)d_in[4];
  const float* y_mask   = (const float*)d_in[5];
  const float* init_cov = (const float*)d_in[6];
  const float* W_ih     = (const float*)d_in[7];
  const float* W_hh     = (const float*)d_in[8];
  const float* b_ih     = (const float*)d_in[9];
  const float* b_hh     = (const float*)d_in[10];
  const float* Wc_att   = (const float*)d_in[11];
  const float* b_att    = (const float*)d_in[12];
  const float* Wv_att   = (const float*)d_in[13];
  const float* bv_att   = (const float*)d_in[14];
  const float* W_comb   = (const float*)d_in[15];
  const float* U_att    = (const float*)d_in[16];
  const float* W_cov    = (const float*)d_in[17];
  const float* W_cat    = (const float*)d_in[18];
  const float* ln_g     = (const float*)d_in[19];
  const float* ln_b     = (const float*)d_in[20];

  float* out = (float*)d_out;
  const size_t SZ_H = (size_t)TY * B * H;
  const size_t SZ_D = (size_t)TY * B * TX;
  float* hs    = out;
  float* cs    = out + SZ_H;
  float* ss    = out + 2 * SZ_H;
  float* atts  = out + 3 * SZ_H;
  float* dists = out + 4 * SZ_H;
  float* Cs    = out + 4 * SZ_H + SZ_D;

  float* ws = (float*)d_ws;
  size_t off = 0;
  float* pctx   = ws + off; off += (size_t)TX * B * C;
  float* pv     = ws + off; off += (size_t)TX * B * C;
  float* xW     = ws + off; off += (size_t)TY * B * G4;
  float* gatesP = ws + off; off += (size_t)8 * B * G4;
  float* hq     = ws + off; off += (size_t)B * C;
  float* ebuf   = ws + off; off += (size_t)B * NH * TX;
  float* attbuf = ws + off; off += (size_t)B * C;
  float* accbuf = ws + off; off += (size_t)B * TX;

  // ---- determine a grid size the cooperative launch is guaranteed to accept
  static int g_nblk = 0;
  if (g_nblk == 0) {
    int maxPerCU = 0;
    if (hipOccupancyMaxActiveBlocksPerMultiprocessor(&maxPerCU, k_steps, 256, 0)
            != hipSuccess || maxPerCU < 1)
      maxPerCU = 1;
    int nCU = 256;
    hipDeviceProp_t prop;
    int dev = 0;
    if (hipGetDevice(&dev) == hipSuccess &&
        hipGetDeviceProperties(&prop, dev) == hipSuccess)
      nCU = prop.multiProcessorCount;
    int nb = maxPerCU * nCU;
    g_nblk = nb > MAXBLK ? MAXBLK : nb;
    if (g_nblk < 1) g_nblk = 256;
  }

  // ---- precompute (big parallel GEMMs, regular launches) ----
  gemm_bias<<<dim3(C / 64, TX * B / 64), 256, 0, stream>>>(
      context, Wc_att, b_att, nullptr, pctx, C, C);
  gemm_bias<<<dim3(C / 64, TX * B / 64), 256, 0, stream>>>(
      context, Wv_att, bv_att, nullptr, pv, C, C);
  gemm_bias<<<dim3(G4 / 64, TY * B / 64), 256, 0, stream>>>(
      y_emb, W_ih, b_ih, b_hh, xW, G4, IN);

  // ---- persistent cooperative kernel for all 128 steps ----
  Params prm;
  prm.h0 = h0; prm.c0 = c0; prm.x_mask = x_mask; prm.y_mask = y_mask;
  prm.init_cov = init_cov;
  prm.W_hh = W_hh; prm.W_comb = W_comb; prm.U_att = U_att; prm.W_cov = W_cov;
  prm.W_cat = W_cat; prm.ln_g = ln_g; prm.ln_b = ln_b;
  prm.xW = xW; prm.pctx = pctx; prm.pv = pv;
  prm.gatesP = gatesP; prm.hq = hq; prm.ebuf = ebuf;
  prm.attbuf = attbuf; prm.accbuf = accbuf;
  prm.hs = hs; prm.cs = cs; prm.ss = ss;
  prm.atts = atts; prm.dists = dists; prm.Cs = Cs;

  void* kargs[] = { (void*)&prm };
  hipLaunchCooperativeKernel((void*)k_steps, dim3(g_nblk), dim3(256), kargs, 0,
                             stream);
}